// Round 3
// baseline (437.654 us; speedup 1.0000x reference)
//
#include <hip/hip_runtime.h>
#include <hip/hip_cooperative_groups.h>

namespace cg = cooperative_groups;

// Problem constants (fixed by setup_inputs / reference)
#define FH 2160
#define FW 3840
#define DH 1080
#define DW 1920
#define RAD 8
#define KS 17
#define INV_KS (1.0f / 17.0f)
#define EPS_GF 1e-3f
#define EPS_LOG 1e-6f
#define EPS_SCALE 1e-4f
#define A_COEF 0.7f

// Guided-filter tile geometry
#define TS 32               // output tile
#define IT (TS + 2 * RAD)   // 48: input tile with halo
#define ITP (IT + 1)        // 49: padded LDS stride

// Cooperative grid: 1024 blocks x 256 threads = 4 blocks/CU on 256 CUs.
// LDS 31.1 KB/block -> 124.4 KB/CU <= 160 KB, so residency is guaranteed.
#define NBLK 1024
#define NTHR 256
#define TOTTHR (NBLK * NTHR)

__device__ __forceinline__ int refl(int p, int n) {
    // jnp.pad 'reflect' (no edge repeat): -1 -> 1, n -> n-2. RAD < n so one fold suffices.
    p = (p < 0) ? -p : p;
    return (p >= n) ? (2 * n - 2 - p) : p;
}

__device__ __forceinline__ float luma(float r, float g, float b) {
    return 0.2126f * r + 0.7152f * g + 0.0722f * b;
}

// LDS union plan (floats):
//   gf1: in  [0,2352)  h1 [2352,3888)  h2 [3888,5424)
//   gf2: inA [0,2352)  inB [2352,4704) hA [4704,6240) hB [6240,7776)
#define SMEM_FLOATS 7776

__global__ void __launch_bounds__(256, 4)
k_fused(const float* __restrict__ x,
        float* __restrict__ D, float* __restrict__ A, float* __restrict__ B,
        float* __restrict__ BASE, float* __restrict__ out) {
    __shared__ float smem[SMEM_FLOATS];
    cg::grid_group grid = cg::this_grid();
    const int t = threadIdx.x;
    const int gtid = blockIdx.x * NTHR + t;

    // ---- Phase A: full-res luma -> log2 -> 2x2 mean downsample ----
    // DOWN=0.5 align_corners=False bilinear == plain 2x2 mean of Y_log.
    for (int idx = gtid; idx < DH * (DW / 2); idx += TOTTHR) {
        int i = idx / (DW / 2);
        int jp = idx - i * (DW / 2);
        size_t base0 = ((size_t)(2 * i) * FW + (size_t)(4 * jp)) * 3;  // 16B aligned
        const float4* r0 = (const float4*)(x + base0);
        const float4* r1 = (const float4*)(x + base0 + (size_t)FW * 3);
        float4 a0 = r0[0], a1 = r0[1], a2 = r0[2];
        float4 b0 = r1[0], b1 = r1[1], b2 = r1[2];
        float f0[12] = {a0.x, a0.y, a0.z, a0.w, a1.x, a1.y, a1.z, a1.w, a2.x, a2.y, a2.z, a2.w};
        float f1[12] = {b0.x, b0.y, b0.z, b0.w, b1.x, b1.y, b1.z, b1.w, b2.x, b2.y, b2.z, b2.w};
        float yl0[4], yl1[4];
#pragma unroll
        for (int q = 0; q < 4; ++q) {
            float Y0 = luma(f0[3 * q], f0[3 * q + 1], f0[3 * q + 2]);
            float Y1 = luma(f1[3 * q], f1[3 * q + 1], f1[3 * q + 2]);
            yl0[q] = __log2f(fmaxf(Y0, EPS_LOG));
            yl1[q] = __log2f(fmaxf(Y1, EPS_LOG));
        }
        float d0 = 0.25f * (yl0[0] + yl0[1] + yl1[0] + yl1[1]);
        float d1 = 0.25f * (yl0[2] + yl0[3] + yl1[2] + yl1[3]);
        *(float2*)(D + (size_t)i * DW + 2 * jp) = make_float2(d0, d1);
    }
    grid.sync();

    // ---- Phase B: GF stage 1: D -> a,b ----
    {
        float* in = smem;
        float* h1 = smem + 2352;
        float* h2 = smem + 3888;
        for (int tile = blockIdx.x; tile < (DW / TS) * ((DH + TS - 1) / TS); tile += NBLK) {
            int tx0 = (tile % (DW / TS)) * TS;
            int ty0 = (tile / (DW / TS)) * TS;
            for (int idx = t; idx < IT * IT; idx += NTHR) {
                int li = idx / IT, lj = idx - li * IT;
                int gi = refl(ty0 - RAD + li, DH);
                int gj = refl(tx0 - RAD + lj, DW);
                in[li * ITP + lj] = D[(size_t)gi * DW + gj];
            }
            __syncthreads();
            for (int idx = t; idx < IT * TS; idx += NTHR) {
                int r = idx >> 5, c = idx & (TS - 1);
                const float* row = &in[r * ITP + c];
                float s1 = 0.f, s2 = 0.f;
#pragma unroll
                for (int k = 0; k < KS; ++k) { float v = row[k]; s1 += v; s2 += v * v; }
                h1[idx] = s1 * INV_KS;
                h2[idx] = s2 * INV_KS;
            }
            __syncthreads();
            for (int idx = t; idx < TS * TS; idx += NTHR) {
                int r = idx >> 5, c = idx & (TS - 1);
                float s1 = 0.f, s2 = 0.f;
#pragma unroll
                for (int k = 0; k < KS; ++k) {
                    s1 += h1[(r + k) * TS + c];
                    s2 += h2[(r + k) * TS + c];
                }
                int gi = ty0 + r, gj = tx0 + c;
                if (gi < DH) {
                    float mI = s1 * INV_KS, mII = s2 * INV_KS;
                    float var = mII - mI * mI;
                    float av = var / (var + EPS_GF);
                    A[(size_t)gi * DW + gj] = av;
                    B[(size_t)gi * DW + gj] = mI - av * mI;
                }
            }
            __syncthreads();
        }
    }
    grid.sync();

    // ---- Phase C: GF stage 2: a,b,D -> base = mean_a * D + mean_b ----
    {
        float* inA = smem;
        float* inB = smem + 2352;
        float* hA = smem + 4704;
        float* hB = smem + 6240;
        for (int tile = blockIdx.x; tile < (DW / TS) * ((DH + TS - 1) / TS); tile += NBLK) {
            int tx0 = (tile % (DW / TS)) * TS;
            int ty0 = (tile / (DW / TS)) * TS;
            for (int idx = t; idx < IT * IT; idx += NTHR) {
                int li = idx / IT, lj = idx - li * IT;
                int gi = refl(ty0 - RAD + li, DH);
                int gj = refl(tx0 - RAD + lj, DW);
                size_t g = (size_t)gi * DW + gj;
                inA[li * ITP + lj] = A[g];
                inB[li * ITP + lj] = B[g];
            }
            __syncthreads();
            for (int idx = t; idx < IT * TS; idx += NTHR) {
                int r = idx >> 5, c = idx & (TS - 1);
                const float* rowa = &inA[r * ITP + c];
                const float* rowb = &inB[r * ITP + c];
                float s1 = 0.f, s2 = 0.f;
#pragma unroll
                for (int k = 0; k < KS; ++k) { s1 += rowa[k]; s2 += rowb[k]; }
                hA[idx] = s1 * INV_KS;
                hB[idx] = s2 * INV_KS;
            }
            __syncthreads();
            for (int idx = t; idx < TS * TS; idx += NTHR) {
                int r = idx >> 5, c = idx & (TS - 1);
                float s1 = 0.f, s2 = 0.f;
#pragma unroll
                for (int k = 0; k < KS; ++k) {
                    s1 += hA[(r + k) * TS + c];
                    s2 += hB[(r + k) * TS + c];
                }
                int gi = ty0 + r, gj = tx0 + c;
                if (gi < DH) {
                    float mA = s1 * INV_KS, mB = s2 * INV_KS;
                    size_t g = (size_t)gi * DW + gj;
                    BASE[g] = mA * D[g] + mB;
                }
            }
            __syncthreads();
        }
    }
    grid.sync();

    // ---- Phase D: upsample base + tone map + scale + clip ----
    for (int idx = gtid; idx < FH * (FW / 4); idx += TOTTHR) {
        int i = idx / (FW / 4);
        int jq = idx - i * (FW / 4);

        float ys = (i + 0.5f) * 0.5f - 0.5f;
        ys = fminf(fmaxf(ys, 0.f), (float)(DH - 1));
        int y0 = (int)ys;
        int y1 = min(y0 + 1, DH - 1);
        float wy = ys - (float)y0;
        const float* brow0 = BASE + (size_t)y0 * DW;
        const float* brow1 = BASE + (size_t)y1 * DW;

        size_t off = ((size_t)i * FW + (size_t)jq * 4) * 3;
        const float4* xin = (const float4*)(x + off);
        float4 v0 = xin[0], v1 = xin[1], v2 = xin[2];
        float px[12] = {v0.x, v0.y, v0.z, v0.w, v1.x, v1.y, v1.z, v1.w,
                        v2.x, v2.y, v2.z, v2.w};
        float po[12];
#pragma unroll
        for (int p = 0; p < 4; ++p) {
            int j = jq * 4 + p;
            float xs = (j + 0.5f) * 0.5f - 0.5f;
            xs = fminf(fmaxf(xs, 0.f), (float)(DW - 1));
            int x0 = (int)xs;
            int x1 = min(x0 + 1, DW - 1);
            float wx = xs - (float)x0;
            float t0 = brow0[x0], t1 = brow0[x1];
            float q0 = brow1[x0], q1 = brow1[x1];
            float top = t0 * (1.f - wx) + t1 * wx;
            float bot = q0 * (1.f - wx) + q1 * wx;
            float Yb = top * (1.f - wy) + bot * wy;

            float cr = px[p * 3 + 0], cg = px[p * 3 + 1], cb = px[p * 3 + 2];
            float Y = luma(cr, cg, cb);
            float Ylog = __log2f(fmaxf(Y, EPS_LOG));
            float Ytm = A_COEF * Yb + (Ylog - Yb);
            float Yout = exp2f(Ytm);
            float scale = Yout / (Y + EPS_SCALE);
            po[p * 3 + 0] = fminf(fmaxf(cr * scale, 0.f), 1.f);
            po[p * 3 + 1] = fminf(fmaxf(cg * scale, 0.f), 1.f);
            po[p * 3 + 2] = fminf(fmaxf(cb * scale, 0.f), 1.f);
        }
        float4* op = (float4*)(out + off);
        op[0] = make_float4(po[0], po[1], po[2], po[3]);
        op[1] = make_float4(po[4], po[5], po[6], po[7]);
        op[2] = make_float4(po[8], po[9], po[10], po[11]);
    }
}

extern "C" void kernel_launch(void* const* d_in, const int* in_sizes, int n_in,
                              void* d_out, int out_size, void* d_ws, size_t ws_size,
                              hipStream_t stream) {
    const float* x = (const float*)d_in[0];
    float* out = (float*)d_out;
    float* ws = (float*)d_ws;
    const size_t DN = (size_t)DW * DH;  // 8.29 MB each

    float* D = ws;
    float* A = ws + DN;
    float* B = ws + 2 * DN;
    float* BASE = ws + 3 * DN;

    void* args[] = {(void*)&x, (void*)&D, (void*)&A, (void*)&B, (void*)&BASE, (void*)&out};
    hipLaunchCooperativeKernel((const void*)k_fused, dim3(NBLK), dim3(NTHR),
                               args, 0, stream);
}

// Round 4
// 103.424 us; speedup vs baseline: 4.2317x; 4.2317x over previous
//
#include <hip/hip_runtime.h>

// Problem constants (fixed by setup_inputs / reference)
#define FH 2160
#define FW 3840
#define DH 1080
#define DW 1920
#define RAD 8
#define KS 17
#define INV_KS (1.0f / 17.0f)
#define EPS_GF 1e-3f
#define EPS_LOG 1e-6f
#define EPS_SCALE 1e-4f
#define A_COEF 0.7f

// Guided-filter tile geometry
#define TS 32               // output tile
#define IT (TS + 2 * RAD)   // 48: input tile with halo
#define ITP (IT + 1)        // 49: padded LDS stride

__device__ __forceinline__ int refl(int p, int n) {
    // jnp.pad 'reflect' (no edge repeat): -1 -> 1, n -> n-2. RAD < n so one fold suffices.
    p = (p < 0) ? -p : p;
    return (p >= n) ? (2 * n - 2 - p) : p;
}

__device__ __forceinline__ float luma(float r, float g, float b) {
    return 0.2126f * r + 0.7152f * g + 0.0722f * b;
}

// ---- 1. full-res luma -> log2 -> 2x2 average downsample ----
// DOWN=0.5 align_corners=False bilinear == plain 2x2 mean of Y_log.
__global__ void k_down(const float* __restrict__ x, float* __restrict__ D) {
    int jp = blockIdx.x * blockDim.x + threadIdx.x;   // pair index, [0, DW/2)
    int i = blockIdx.y;
    if (jp >= DW / 2) return;
    size_t base0 = ((size_t)(2 * i) * FW + (size_t)(4 * jp)) * 3;  // floats; 16B aligned
    const float4* r0 = (const float4*)(x + base0);
    const float4* r1 = (const float4*)(x + base0 + (size_t)FW * 3);
    float4 a0 = r0[0], a1 = r0[1], a2 = r0[2];
    float4 b0 = r1[0], b1 = r1[1], b2 = r1[2];
    float f0[12] = {a0.x, a0.y, a0.z, a0.w, a1.x, a1.y, a1.z, a1.w, a2.x, a2.y, a2.z, a2.w};
    float f1[12] = {b0.x, b0.y, b0.z, b0.w, b1.x, b1.y, b1.z, b1.w, b2.x, b2.y, b2.z, b2.w};
    float yl0[4], yl1[4];
#pragma unroll
    for (int q = 0; q < 4; ++q) {
        float Y0 = luma(f0[3 * q], f0[3 * q + 1], f0[3 * q + 2]);
        float Y1 = luma(f1[3 * q], f1[3 * q + 1], f1[3 * q + 2]);
        yl0[q] = __log2f(fmaxf(Y0, EPS_LOG));
        yl1[q] = __log2f(fmaxf(Y1, EPS_LOG));
    }
    float d0 = 0.25f * (yl0[0] + yl0[1] + yl1[0] + yl1[1]);
    float d1 = 0.25f * (yl0[2] + yl0[3] + yl1[2] + yl1[3]);
    *(float2*)(D + (size_t)i * DW + 2 * jp) = make_float2(d0, d1);
}

// ---- 2. fused GF stage 1: D -> a,b  (sliding-window hbox+vbox) ----
__global__ void k_gf1(const float* __restrict__ D,
                      float* __restrict__ a, float* __restrict__ b) {
    __shared__ float in[IT * ITP];   // 48 x 49
    __shared__ float h1[IT * TS];    // 48 x 32
    __shared__ float h2[IT * TS];
    int tx0 = blockIdx.x * TS, ty0 = blockIdx.y * TS;
    int t = threadIdx.x;

    for (int idx = t; idx < IT * IT; idx += 256) {
        int li = idx / IT, lj = idx - li * IT;
        in[li * ITP + lj] = D[(size_t)refl(ty0 - RAD + li, DH) * DW + refl(tx0 - RAD + lj, DW)];
    }
    __syncthreads();

    // hbox: worker (r, half) covers out cols [16*half, 16*half+16)
    if (t < IT * 2) {
        int r = t >> 1, half = t & 1;
        const float* row = &in[r * ITP + half * 16];
        float s1 = 0.f, s2 = 0.f;
#pragma unroll
        for (int k = 0; k < KS; ++k) { float v = row[k]; s1 += v; s2 += v * v; }
        int base = r * TS + half * 16;
        h1[base] = s1 * INV_KS;
        h2[base] = s2 * INV_KS;
        for (int c = 1; c < 16; ++c) {
            float vo = row[c - 1], vi = row[c + 16];
            s1 += vi - vo;
            s2 += vi * vi - vo * vo;
            h1[base + c] = s1 * INV_KS;
            h2[base + c] = s2 * INV_KS;
        }
    }
    __syncthreads();

    // vbox: worker (c, half) covers out rows [16*half, 16*half+16)
    if (t < 64) {
        int c = t & 31, half = t >> 5;
        int r0 = half * 16;
        float s1 = 0.f, s2 = 0.f;
#pragma unroll
        for (int k = 0; k < KS; ++k) {
            s1 += h1[(r0 + k) * TS + c];
            s2 += h2[(r0 + k) * TS + c];
        }
        for (int rr = 0; rr < 16; ++rr) {
            float mI = s1 * INV_KS, mII = s2 * INV_KS;
            float var = mII - mI * mI;
            float av = var / (var + EPS_GF);
            int gi = ty0 + r0 + rr, gj = tx0 + c;
            if (gi < DH) {
                size_t g = (size_t)gi * DW + gj;
                a[g] = av;
                b[g] = mI - av * mI;
            }
            if (rr < 15) {
                int rout = (r0 + rr) * TS + c, rin = (r0 + rr + KS) * TS + c;
                s1 += h1[rin] - h1[rout];
                s2 += h2[rin] - h2[rout];
            }
        }
    }
}

// ---- 3. fused GF stage 2: a,b,D -> base = mean_a * D + mean_b ----
__global__ void k_gf2(const float* __restrict__ A, const float* __restrict__ B,
                      const float* __restrict__ D, float* __restrict__ base) {
    __shared__ float inA[IT * ITP];
    __shared__ float inB[IT * ITP];
    __shared__ float hA[IT * TS];
    __shared__ float hB[IT * TS];
    int tx0 = blockIdx.x * TS, ty0 = blockIdx.y * TS;
    int t = threadIdx.x;

    for (int idx = t; idx < IT * IT; idx += 256) {
        int li = idx / IT, lj = idx - li * IT;
        size_t g = (size_t)refl(ty0 - RAD + li, DH) * DW + refl(tx0 - RAD + lj, DW);
        inA[li * ITP + lj] = A[g];
        inB[li * ITP + lj] = B[g];
    }
    __syncthreads();

    if (t < IT * 2) {
        int r = t >> 1, half = t & 1;
        const float* rowa = &inA[r * ITP + half * 16];
        const float* rowb = &inB[r * ITP + half * 16];
        float s1 = 0.f, s2 = 0.f;
#pragma unroll
        for (int k = 0; k < KS; ++k) { s1 += rowa[k]; s2 += rowb[k]; }
        int base_i = r * TS + half * 16;
        hA[base_i] = s1 * INV_KS;
        hB[base_i] = s2 * INV_KS;
        for (int c = 1; c < 16; ++c) {
            s1 += rowa[c + 16] - rowa[c - 1];
            s2 += rowb[c + 16] - rowb[c - 1];
            hA[base_i + c] = s1 * INV_KS;
            hB[base_i + c] = s2 * INV_KS;
        }
    }
    __syncthreads();

    if (t < 64) {
        int c = t & 31, half = t >> 5;
        int r0 = half * 16;
        float s1 = 0.f, s2 = 0.f;
#pragma unroll
        for (int k = 0; k < KS; ++k) {
            s1 += hA[(r0 + k) * TS + c];
            s2 += hB[(r0 + k) * TS + c];
        }
        for (int rr = 0; rr < 16; ++rr) {
            float mA = s1 * INV_KS, mB = s2 * INV_KS;
            int gi = ty0 + r0 + rr, gj = tx0 + c;
            if (gi < DH) {
                size_t g = (size_t)gi * DW + gj;
                base[g] = mA * D[g] + mB;
            }
            if (rr < 15) {
                int rout = (r0 + rr) * TS + c, rin = (r0 + rr + KS) * TS + c;
                s1 += hA[rin] - hA[rout];
                s2 += hB[rin] - hB[rout];
            }
        }
    }
}

// ---- 4. upsample base + tone map + scale + clip ----
__global__ void k_final(const float* __restrict__ x, const float* __restrict__ base,
                        float* __restrict__ out) {
    int i = blockIdx.y;
    int jq = blockIdx.x * blockDim.x + threadIdx.x;  // quad of 4 pixels
    if (jq >= FW / 4) return;

    float ys = (i + 0.5f) * 0.5f - 0.5f;
    ys = fminf(fmaxf(ys, 0.f), (float)(DH - 1));
    int y0 = (int)ys;
    int y1 = min(y0 + 1, DH - 1);
    float wy = ys - (float)y0;
    const float* brow0 = base + (size_t)y0 * DW;
    const float* brow1 = base + (size_t)y1 * DW;

    size_t off = ((size_t)i * FW + (size_t)jq * 4) * 3;
    const float4* xin = (const float4*)(x + off);
    float4 v0 = xin[0], v1 = xin[1], v2 = xin[2];
    float px[12] = {v0.x, v0.y, v0.z, v0.w, v1.x, v1.y, v1.z, v1.w,
                    v2.x, v2.y, v2.z, v2.w};
    float po[12];
#pragma unroll
    for (int p = 0; p < 4; ++p) {
        int j = jq * 4 + p;
        float xs = (j + 0.5f) * 0.5f - 0.5f;
        xs = fminf(fmaxf(xs, 0.f), (float)(DW - 1));
        int x0 = (int)xs;
        int x1 = min(x0 + 1, DW - 1);
        float wx = xs - (float)x0;
        float t0 = brow0[x0], t1 = brow0[x1];
        float q0 = brow1[x0], q1 = brow1[x1];
        float top = t0 * (1.f - wx) + t1 * wx;
        float bot = q0 * (1.f - wx) + q1 * wx;
        float Yb = top * (1.f - wy) + bot * wy;

        float cr = px[p * 3 + 0], cg = px[p * 3 + 1], cb = px[p * 3 + 2];
        float Y = luma(cr, cg, cb);
        float Ylog = __log2f(fmaxf(Y, EPS_LOG));
        float Ytm = A_COEF * Yb + (Ylog - Yb);
        float Yout = exp2f(Ytm);
        float scale = Yout / (Y + EPS_SCALE);
        po[p * 3 + 0] = fminf(fmaxf(cr * scale, 0.f), 1.f);
        po[p * 3 + 1] = fminf(fmaxf(cg * scale, 0.f), 1.f);
        po[p * 3 + 2] = fminf(fmaxf(cb * scale, 0.f), 1.f);
    }
    float4* op = (float4*)(out + off);
    op[0] = make_float4(po[0], po[1], po[2], po[3]);
    op[1] = make_float4(po[4], po[5], po[6], po[7]);
    op[2] = make_float4(po[8], po[9], po[10], po[11]);
}

extern "C" void kernel_launch(void* const* d_in, const int* in_sizes, int n_in,
                              void* d_out, int out_size, void* d_ws, size_t ws_size,
                              hipStream_t stream) {
    const float* x = (const float*)d_in[0];
    float* out = (float*)d_out;
    float* ws = (float*)d_ws;
    const size_t DN = (size_t)DW * DH;  // 8.29 MB each

    float* D = ws;
    float* A = ws + DN;
    float* B = ws + 2 * DN;
    float* BASE = ws + 3 * DN;

    dim3 blk(256);

    dim3 grdDown((DW / 2 + 255) / 256, DH);
    k_down<<<grdDown, blk, 0, stream>>>(x, D);

    dim3 grdGF(DW / TS, (DH + TS - 1) / TS);  // 60 x 34
    k_gf1<<<grdGF, blk, 0, stream>>>(D, A, B);
    k_gf2<<<grdGF, blk, 0, stream>>>(A, B, D, BASE);

    dim3 grdF((FW / 4 + 255) / 256, FH);
    k_final<<<grdF, blk, 0, stream>>>(x, BASE, out);
}

// Round 5
// 77.123 us; speedup vs baseline: 5.6748x; 1.3410x over previous
//
#include <hip/hip_runtime.h>

// Problem constants (fixed by setup_inputs / reference)
#define FH 2160
#define FW 3840
#define DH 1080
#define DW 1920
#define RAD 8
#define KS 17
#define INV_KS (1.0f / 17.0f)
#define EPS_GF 1e-3f
#define EPS_LOG 1e-6f
#define EPS_SCALE 1e-4f
#define A_COEF 0.7f

// K1 geometry: 32x32 core of D/a/b per block, D halo tile 48x48 built from x 96x96
#define TS 32
#define IT 48               // TS + 2*RAD
#define ITP 49              // padded stride

// K2 geometry: 64x64 output px per block; base tile 34x34 (32 + bilinear +/-1 halo);
// a/b tile 50x50 (34 + 2*RAD)
#define AT 50
#define ATP 51
#define BT 34
#define BTP 35

// Grid: 60 x 34 tiles = 2040 blocks (2040 % 8 == 0 -> simple XCD swizzle is bijective)
#define NTILES 2040
#define TPX 255             // tiles per XCD

__device__ __forceinline__ int refl(int p, int n) {
    // jnp.pad 'reflect' (no edge repeat): -1 -> 1, n -> n-2. Offsets < n so one fold suffices.
    p = (p < 0) ? -p : p;
    return (p >= n) ? (2 * n - 2 - p) : p;
}

__device__ __forceinline__ float luma3(float r, float g, float b) {
    return 0.2126f * r + 0.7152f * g + 0.0722f * b;
}

// ---- K1: x -> D, a, b  (downsample fused with GF stage 1) ----
__global__ void __launch_bounds__(256, 4)
k_gf_front(const float* __restrict__ x, float* __restrict__ Dg,
           float* __restrict__ Ag, float* __restrict__ Bg) {
    __shared__ float inD[IT * ITP];   // 48x49
    __shared__ float h1[IT * TS];     // 48x32
    __shared__ float h2[IT * TS];
    int bid = blockIdx.x;
    int swz = (bid & 7) * TPX + (bid >> 3);   // XCD-contiguous raster strips
    int bx = swz % 60, by = swz / 60;
    int tx0 = bx * TS, ty0 = by * TS;
    int t = threadIdx.x;

    // Build D halo tile directly from x: D(gi,gj) = mean of log2(max(luma,eps)) over 2x2 px.
    // (DOWN=0.5 align_corners=False bilinear == exact 2x2 mean.)
    for (int s = t; s < IT * IT; s += 256) {          // 2304 = 9*256 exact
        int li = s / IT, lj = s - li * IT;
        int gi = refl(ty0 - RAD + li, DH);
        int gj = refl(tx0 - RAD + lj, DW);
        const float* p0 = x + ((size_t)(2 * gi) * FW + (size_t)(2 * gj)) * 3;
        const float* p1 = p0 + (size_t)FW * 3;
        float2 a0 = *(const float2*)(p0);
        float2 a1 = *(const float2*)(p0 + 2);
        float2 a2 = *(const float2*)(p0 + 4);
        float2 b0 = *(const float2*)(p1);
        float2 b1 = *(const float2*)(p1 + 2);
        float2 b2 = *(const float2*)(p1 + 4);
        float y00 = luma3(a0.x, a0.y, a1.x);
        float y01 = luma3(a1.y, a2.x, a2.y);
        float y10 = luma3(b0.x, b0.y, b1.x);
        float y11 = luma3(b1.y, b2.x, b2.y);
        inD[li * ITP + lj] = 0.25f * (__log2f(fmaxf(y00, EPS_LOG)) +
                                      __log2f(fmaxf(y01, EPS_LOG)) +
                                      __log2f(fmaxf(y10, EPS_LOG)) +
                                      __log2f(fmaxf(y11, EPS_LOG)));
    }
    __syncthreads();

    // hbox of I and I*I
    for (int idx = t; idx < IT * TS; idx += 256) {
        int r = idx >> 5, c = idx & 31;
        const float* row = &inD[r * ITP + c];
        float s1 = 0.f, s2 = 0.f;
#pragma unroll
        for (int k = 0; k < KS; ++k) { float v = row[k]; s1 += v; s2 += v * v; }
        h1[idx] = s1 * INV_KS;
        h2[idx] = s2 * INV_KS;
    }
    __syncthreads();

    // vbox -> a,b ; also write D core
    for (int idx = t; idx < TS * TS; idx += 256) {
        int r = idx >> 5, c = idx & 31;
        int gi = ty0 + r;
        if (gi < DH) {
            float s1 = 0.f, s2 = 0.f;
#pragma unroll
            for (int k = 0; k < KS; ++k) {
                s1 += h1[(r + k) * TS + c];
                s2 += h2[(r + k) * TS + c];
            }
            float mI = s1 * INV_KS, mII = s2 * INV_KS;
            float var = mII - mI * mI;
            float av = var / (var + EPS_GF);
            size_t g = (size_t)gi * DW + tx0 + c;
            Ag[g] = av;
            Bg[g] = mI - av * mI;
            Dg[g] = inD[(r + RAD) * ITP + c + RAD];
        }
    }
}

// ---- K2: a,b,D,x -> out  (GF stage 2 fused with upsample + tonemap) ----
__global__ void __launch_bounds__(256)
k_gf_back(const float* __restrict__ x, const float* __restrict__ Ag,
          const float* __restrict__ Bg, const float* __restrict__ Dg,
          float* __restrict__ out) {
    __shared__ float inA[AT * ATP];      // 50x51
    __shared__ float inB[AT * ATP];
    __shared__ float hA[AT * BT];        // 50x34
    __shared__ float hB[AT * BT];
    __shared__ float baseT[BT * BTP];    // 34x35
    int bid = blockIdx.x;
    int swz = (bid & 7) * TPX + (bid >> 3);
    int bx = swz % 60, by = swz / 60;
    int ox0 = bx * 64, oy0 = by * 64;
    int bh0 = by * 32 - 1, bw0 = bx * 32 - 1;   // base tile origin (incl -1 bilinear halo)
    int ah0 = bh0 - RAD, aw0 = bw0 - RAD;       // a/b tile origin
    int t = threadIdx.x;

    for (int s = t; s < AT * AT; s += 256) {
        int li = s / AT, lj = s - li * AT;
        size_t g = (size_t)refl(ah0 + li, DH) * DW + refl(aw0 + lj, DW);
        inA[li * ATP + lj] = Ag[g];
        inB[li * ATP + lj] = Bg[g];
    }
    __syncthreads();

    for (int idx = t; idx < AT * BT; idx += 256) {
        int r = idx / BT, c = idx - r * BT;
        const float* ra = &inA[r * ATP + c];
        const float* rb = &inB[r * ATP + c];
        float s1 = 0.f, s2 = 0.f;
#pragma unroll
        for (int k = 0; k < KS; ++k) { s1 += ra[k]; s2 += rb[k]; }
        hA[r * BT + c] = s1 * INV_KS;
        hB[r * BT + c] = s2 * INV_KS;
    }
    __syncthreads();

    for (int idx = t; idx < BT * BT; idx += 256) {
        int r = idx / BT, c = idx - r * BT;
        float s1 = 0.f, s2 = 0.f;
#pragma unroll
        for (int k = 0; k < KS; ++k) {
            s1 += hA[(r + k) * BT + c];
            s2 += hB[(r + k) * BT + c];
        }
        size_t g = (size_t)refl(bh0 + r, DH) * DW + refl(bw0 + c, DW);
        baseT[r * BTP + c] = (s1 * INV_KS) * Dg[g] + s2 * INV_KS;
    }
    __syncthreads();

    // upsample base from LDS + tonemap + scale + clip; 64 rows x 16 quads of 4 px
    for (int q = t; q < 64 * 16; q += 256) {
        int qi = q >> 4, qj = q & 15;
        int oy = oy0 + qi;
        if (oy < FH) {
            float ys = fminf(fmaxf((oy + 0.5f) * 0.5f - 0.5f, 0.f), (float)(DH - 1));
            int y0 = (int)ys;
            int y1 = min(y0 + 1, DH - 1);
            float wy = ys - (float)y0;
            const float* br0 = &baseT[(y0 - bh0) * BTP];
            const float* br1 = &baseT[(y1 - bh0) * BTP];

            size_t off = ((size_t)oy * FW + (size_t)(ox0 + 4 * qj)) * 3;
            const float4* xin = (const float4*)(x + off);
            float4 v0 = xin[0], v1 = xin[1], v2 = xin[2];
            float px[12] = {v0.x, v0.y, v0.z, v0.w, v1.x, v1.y, v1.z, v1.w,
                            v2.x, v2.y, v2.z, v2.w};
            float po[12];
#pragma unroll
            for (int p = 0; p < 4; ++p) {
                int ox = ox0 + 4 * qj + p;
                float xs = fminf(fmaxf((ox + 0.5f) * 0.5f - 0.5f, 0.f), (float)(DW - 1));
                int x0 = (int)xs;
                int x1 = min(x0 + 1, DW - 1);
                float wx = xs - (float)x0;
                int c0 = x0 - bw0, c1 = x1 - bw0;
                float top = br0[c0] * (1.f - wx) + br0[c1] * wx;
                float bot = br1[c0] * (1.f - wx) + br1[c1] * wx;
                float Yb = top * (1.f - wy) + bot * wy;

                float cr = px[3 * p], cg = px[3 * p + 1], cb = px[3 * p + 2];
                float Y = luma3(cr, cg, cb);
                float Ylog = __log2f(fmaxf(Y, EPS_LOG));
                float Yout = exp2f(A_COEF * Yb + (Ylog - Yb));
                float sc = Yout / (Y + EPS_SCALE);
                po[3 * p + 0] = fminf(fmaxf(cr * sc, 0.f), 1.f);
                po[3 * p + 1] = fminf(fmaxf(cg * sc, 0.f), 1.f);
                po[3 * p + 2] = fminf(fmaxf(cb * sc, 0.f), 1.f);
            }
            float4* op = (float4*)(out + off);
            op[0] = make_float4(po[0], po[1], po[2], po[3]);
            op[1] = make_float4(po[4], po[5], po[6], po[7]);
            op[2] = make_float4(po[8], po[9], po[10], po[11]);
        }
    }
}

extern "C" void kernel_launch(void* const* d_in, const int* in_sizes, int n_in,
                              void* d_out, int out_size, void* d_ws, size_t ws_size,
                              hipStream_t stream) {
    const float* x = (const float*)d_in[0];
    float* out = (float*)d_out;
    float* ws = (float*)d_ws;
    const size_t DN = (size_t)DW * DH;  // 8.29 MB each

    float* D = ws;
    float* A = ws + DN;
    float* B = ws + 2 * DN;

    k_gf_front<<<dim3(NTILES), dim3(256), 0, stream>>>(x, D, A, B);
    k_gf_back <<<dim3(NTILES), dim3(256), 0, stream>>>(x, A, B, D, out);
}